// Round 5
// baseline (194.629 us; speedup 1.0000x reference)
//
#include <hip/hip_runtime.h>
#include <math.h>

#define BB 32
#define HH 32
#define KHH 8
#define DD 128
#define LL 4096
#define GG 4
#define SCALE 0.08838834764831845f

#define NTHREADS 512
#define NW 8
#define SPLITS 8
#define RPB (LL / SPLITS)      // 512 rows per block
#define RPW (RPB / NW)         // 64 rows per wave

// workspace layout (floats):
//   ws_o [BB][SPLITS][HH][DD]  = 1048576 floats (partial numerators)
//   ws_ms[BB][SPLITS][HH][2]   = 16384  floats (m, den per partial)
#define WS_O_FLOATS   (BB * SPLITS * HH * DD)
#define WS_MS_FLOATS  (BB * SPLITS * HH * 2)
#define WS_NEED_BYTES ((size_t)(WS_O_FLOATS + WS_MS_FLOATS) * 4)

typedef float f4 __attribute__((ext_vector_type(4)));

// ============================ kernel 1 ===================================
// block = (b, l-split): reads COMPLETE contiguous K/V rows (4 KB each).
// wave = one row at a time; 8 lanes per kh, 16 floats per lane.
__global__ __launch_bounds__(NTHREADS, 2)
void attn_part(const float* __restrict__ q,
               const float* __restrict__ knew,
               const float* __restrict__ vnew,
               const float* __restrict__ kc,
               const float* __restrict__ vc,
               const int* __restrict__ kvi,
               float* __restrict__ ws_o,
               float* __restrict__ ws_ms) {
  __shared__ int   lds_val[RPB];              // 2 KB
  __shared__ int   lds_loc[BB];
  __shared__ float o_lds[NW][KHH][GG][DD];    // 128 KB
  __shared__ float m_lds[NW][KHH][GG];
  __shared__ float s_lds[NW][KHH][GG];

  const int tid  = threadIdx.x;
  const int b    = blockIdx.x >> 3;
  const int sp   = blockIdx.x & 7;
  const int w    = tid >> 6;
  const int lane = tid & 63;
  const int kh   = lane >> 3;     // 8 lanes per kv-head
  const int sub  = lane & 7;      // chunk within head
  const int d0   = sub * 16;      // dims [d0, d0+16)

  const int base = sp * RPB;

  // ---- row-source table for this block's l-range
  if (tid < BB) lds_loc[tid] = kvi[tid * LL + (LL - 1)];
  __syncthreads();
  {
    int idx = kvi[b * LL + base + tid];   // NTHREADS == RPB
    int val = idx;
#pragma unroll
    for (int j = 0; j < BB; ++j)
      if (lds_loc[j] == idx) val = -(j + 1);
    lds_val[tid] = val;
  }
  __syncthreads();

  // ---- q fragments: 4 group-heads x 16 dims (as 4 f4) per lane
  f4 qf[GG][4];
#pragma unroll
  for (int g = 0; g < GG; ++g) {
    const float* qp = q + ((size_t)b * HH + (kh * GG + g)) * DD + d0;
#pragma unroll
    for (int c = 0; c < 4; ++c) qf[g][c] = *(const f4*)(qp + c * 4);
  }

  f4 o[GG][4];
  float m[GG], sden[GG];
#pragma unroll
  for (int g = 0; g < GG; ++g) {
    m[g] = -INFINITY; sden[g] = 0.f;
#pragma unroll
    for (int c = 0; c < 4; ++c) o[g][c] = (f4){0.f, 0.f, 0.f, 0.f};
  }

  // per-wave linear sweep: wave w owns rows [w*RPW, (w+1)*RPW) of the split
  auto addr = [&](int it, const float*& kp, const float*& vp) {
    int l   = w * RPW + it;
    int val = lds_val[l];
    int row = (val < 0) ? (-val - 1) : val;
    const float* kb = (val < 0) ? knew : kc;
    const float* vb = (val < 0) ? vnew : vc;
    size_t off = (size_t)row * (KHH * DD) + lane * 16;  // full-row: lane*64B
    kp = kb + off;
    vp = vb + off;
  };

#define LOADKV(it, K0, K1, K2, K3, V0, V1, V2, V3)  \
  { const float *kp_, *vp_; addr(it, kp_, vp_);     \
    K0 = *(const f4*)kp_;        K1 = *(const f4*)(kp_ + 4);  \
    K2 = *(const f4*)(kp_ + 8);  K3 = *(const f4*)(kp_ + 12); \
    V0 = *(const f4*)vp_;        V1 = *(const f4*)(vp_ + 4);  \
    V2 = *(const f4*)(vp_ + 8);  V3 = *(const f4*)(vp_ + 12); }

  auto compute = [&](f4 k0, f4 k1, f4 k2, f4 k3,
                     f4 v0, f4 v1, f4 v2, f4 v3) {
    float sc[GG];
#pragma unroll
    for (int g = 0; g < GG; ++g) {
      f4 t = qf[g][0] * k0 + qf[g][1] * k1 + qf[g][2] * k2 + qf[g][3] * k3;
      float s1 = t[0] + t[1] + t[2] + t[3];
#pragma unroll
      for (int msk = 1; msk < 8; msk <<= 1)     // reduce across 8-lane group
        s1 += __shfl_xor(s1, msk);
      sc[g] = s1 * SCALE;
    }
#pragma unroll
    for (int g = 0; g < GG; ++g) {
      if (sc[g] > m[g]) {
        float so = __expf(m[g] - sc[g]);
        m[g] = sc[g];
        sden[g] *= so;
#pragma unroll
        for (int c = 0; c < 4; ++c) o[g][c] *= so;
      }
      float p = __expf(sc[g] - m[g]);
      sden[g] += p;
      o[g][0] += p * v0; o[g][1] += p * v1; o[g][2] += p * v2; o[g][3] += p * v3;
    }
  };

  // ---- 2-buffer pipelined row loop (RPW = 64, even)
  f4 kA0, kA1, kA2, kA3, vA0, vA1, vA2, vA3;
  f4 kB0, kB1, kB2, kB3, vB0, vB1, vB2, vB3;
  LOADKV(0, kA0, kA1, kA2, kA3, vA0, vA1, vA2, vA3);
#pragma unroll 1
  for (int it = 0; it < RPW; it += 2) {
    LOADKV(it + 1, kB0, kB1, kB2, kB3, vB0, vB1, vB2, vB3);
    compute(kA0, kA1, kA2, kA3, vA0, vA1, vA2, vA3);
    if (it + 2 < RPW) LOADKV(it + 2, kA0, kA1, kA2, kA3, vA0, vA1, vA2, vA3);
    compute(kB0, kB1, kB2, kB3, vB0, vB1, vB2, vB3);
  }

  // ---- per-wave partials to LDS
#pragma unroll
  for (int g = 0; g < GG; ++g)
#pragma unroll
    for (int c = 0; c < 4; ++c)
      *(f4*)&o_lds[w][kh][g][d0 + c * 4] = o[g][c];
  if (sub == 0) {
#pragma unroll
    for (int g = 0; g < GG; ++g) { m_lds[w][kh][g] = m[g]; s_lds[w][kh][g] = sden[g]; }
  }
  __syncthreads();

  // ---- cross-wave merge; write split-partial (num, m, den) to workspace
#pragma unroll
  for (int rep = 0; rep < (KHH * GG * DD) / NTHREADS; ++rep) {
    int idx = rep * NTHREADS + tid;
    int kh2 = idx >> 9;
    int g2  = (idx >> 7) & 3;
    int d   = idx & 127;
    float M = -INFINITY;
#pragma unroll
    for (int wv = 0; wv < NW; ++wv) M = fmaxf(M, m_lds[wv][kh2][g2]);
    float den = 0.f, num = 0.f;
#pragma unroll
    for (int wv = 0; wv < NW; ++wv) {
      float wt = __expf(m_lds[wv][kh2][g2] - M);
      den += wt * s_lds[wv][kh2][g2];
      num += wt * o_lds[wv][kh2][g2][d];
    }
    int h    = kh2 * GG + g2;
    int part = (b * SPLITS + sp) * HH + h;
    ws_o[(size_t)part * DD + d] = num;
    if (d == 0) { ws_ms[part * 2] = M; ws_ms[part * 2 + 1] = den; }
  }
}

// ============================ kernel 2 ===================================
// merge the 8 l-split partials per (b, h); write final output.
__global__ __launch_bounds__(NTHREADS)
void attn_merge(const float* __restrict__ ws_o,
                const float* __restrict__ ws_ms,
                float* __restrict__ out) {
  const int b  = blockIdx.x >> 3;
  const int kh = blockIdx.x & 7;
  const int g  = threadIdx.x >> 7;
  const int d  = threadIdx.x & 127;
  const int h  = kh * GG + g;

  float M = -INFINITY;
#pragma unroll
  for (int s = 0; s < SPLITS; ++s)
    M = fmaxf(M, ws_ms[((b * SPLITS + s) * HH + h) * 2]);
  float den = 0.f, num = 0.f;
#pragma unroll
  for (int s = 0; s < SPLITS; ++s) {
    int part = (b * SPLITS + s) * HH + h;
    float wt = __expf(ws_ms[part * 2] - M);
    den += wt * ws_ms[part * 2 + 1];
    num += wt * ws_o[(size_t)part * DD + d];
  }
  out[((size_t)b * HH + h) * DD + d] = num / den;
}

// ====================== fallback (R1 structure) ==========================
#define FNIT (LL / (NW * 4))
__global__ __launch_bounds__(NTHREADS, 1)
void attn_decode_fb(const float* __restrict__ q,
                    const float* __restrict__ knew,
                    const float* __restrict__ vnew,
                    const float* __restrict__ kc,
                    const float* __restrict__ vc,
                    const int* __restrict__ kvi,
                    float* __restrict__ out) {
  __shared__ int   lds_val[LL];
  __shared__ float o_lds[NW][GG][DD];
  __shared__ float m_lds[NW][GG];
  __shared__ float s_lds[NW][GG];
  __shared__ int   lds_loc[BB];

  const int tid  = threadIdx.x;
  const int b    = blockIdx.x >> 3;
  const int kh   = blockIdx.x & 7;
  const int w    = tid >> 6;
  const int lane = tid & 63;
  const int qid  = lane >> 4;
  const int i16  = lane & 15;

  if (tid < BB) lds_loc[tid] = kvi[tid * LL + (LL - 1)];
  __syncthreads();
  for (int l = tid; l < LL; l += NTHREADS) {
    int idx = kvi[b * LL + l];
    int val = idx;
#pragma unroll
    for (int j = 0; j < BB; ++j)
      if (lds_loc[j] == idx) val = -(j + 1);
    lds_val[l] = val;
  }
  __syncthreads();

  const int khq = kh * GG;
  float qf[GG][8];
#pragma unroll
  for (int g = 0; g < GG; ++g) {
    const float* qp = q + ((size_t)b * HH + (khq + g)) * DD + i16 * 8;
#pragma unroll
    for (int j = 0; j < 8; ++j) qf[g][j] = qp[j];
  }

  float m[GG], s[GG], o[GG][8];
#pragma unroll
  for (int g = 0; g < GG; ++g) {
    m[g] = -INFINITY; s[g] = 0.f;
#pragma unroll
    for (int j = 0; j < 8; ++j) o[g][j] = 0.f;
  }

  const size_t khoff = (size_t)kh * DD + i16 * 8;
  auto addr = [&](int it, const float*& kp, const float*& vp) {
    int l   = it * 32 + w * 4 + qid;
    int val = lds_val[l];
    int row = (val < 0) ? (-val - 1) : val;
    const float* kb = (val < 0) ? knew : kc;
    const float* vb = (val < 0) ? vnew : vc;
    size_t off = ((size_t)row * (KHH * DD)) + khoff;
    kp = kb + off; vp = vb + off;
  };

  const float *kp, *vp;
  addr(0, kp, vp);
  float4 ka  = *(const float4*)kp;
  float4 kb4 = *(const float4*)(kp + 4);
  float4 va  = *(const float4*)vp;
  float4 vb4 = *(const float4*)(vp + 4);

  for (int it = 0; it < FNIT; ++it) {
    float4 nka, nkb, nva, nvb;
    if (it + 1 < FNIT) {
      const float *nkp, *nvp;
      addr(it + 1, nkp, nvp);
      nka = *(const float4*)nkp; nkb = *(const float4*)(nkp + 4);
      nva = *(const float4*)nvp; nvb = *(const float4*)(nvp + 4);
    } else { nka = ka; nkb = kb4; nva = va; nvb = vb4; }

#pragma unroll
    for (int g = 0; g < GG; ++g) {
      float sc = qf[g][0]*ka.x  + qf[g][1]*ka.y  + qf[g][2]*ka.z  + qf[g][3]*ka.w
               + qf[g][4]*kb4.x + qf[g][5]*kb4.y + qf[g][6]*kb4.z + qf[g][7]*kb4.w;
#pragma unroll
      for (int msk = 1; msk < 16; msk <<= 1) sc += __shfl_xor(sc, msk);
      sc *= SCALE;
      if (sc > m[g]) {
        float so = __expf(m[g] - sc);
        m[g] = sc; s[g] *= so;
#pragma unroll
        for (int j = 0; j < 8; ++j) o[g][j] *= so;
      }
      float p = __expf(sc - m[g]);
      s[g] += p;
      o[g][0] += p * va.x;  o[g][1] += p * va.y;  o[g][2] += p * va.z;  o[g][3] += p * va.w;
      o[g][4] += p * vb4.x; o[g][5] += p * vb4.y; o[g][6] += p * vb4.z; o[g][7] += p * vb4.w;
    }
    ka = nka; kb4 = nkb; va = nva; vb4 = nvb;
  }

#pragma unroll
  for (int g = 0; g < GG; ++g) {
#pragma unroll
    for (int off = 16; off < 64; off <<= 1) {
      float m2 = __shfl_xor(m[g], off);
      float s2 = __shfl_xor(s[g], off);
      float M  = fmaxf(m[g], m2);
      float w1 = __expf(m[g] - M);
      float w2 = __expf(m2 - M);
      s[g] = w1 * s[g] + w2 * s2;
#pragma unroll
      for (int j = 0; j < 8; ++j) {
        float o2 = __shfl_xor(o[g][j], off);
        o[g][j] = w1 * o[g][j] + w2 * o2;
      }
      m[g] = M;
    }
  }

  if (lane < 16) {
#pragma unroll
    for (int g = 0; g < GG; ++g) {
#pragma unroll
      for (int j = 0; j < 8; ++j) o_lds[w][g][i16 * 8 + j] = o[g][j];
      if (lane == 0) { m_lds[w][g] = m[g]; s_lds[w][g] = s[g]; }
    }
  }
  __syncthreads();
  {
    int g = tid >> 7;
    int d = tid & 127;
    float M = -INFINITY;
#pragma unroll
    for (int wv = 0; wv < NW; ++wv) M = fmaxf(M, m_lds[wv][g]);
    float ss = 0.f, oo = 0.f;
#pragma unroll
    for (int wv = 0; wv < NW; ++wv) {
      float wt = __expf(m_lds[wv][g] - M);
      ss += wt * s_lds[wv][g];
      oo += wt * o_lds[wv][g][d];
    }
    out[((size_t)b * HH + (khq + g)) * DD + d] = oo / ss;
  }
}

extern "C" void kernel_launch(void* const* d_in, const int* in_sizes, int n_in,
                              void* d_out, int out_size, void* d_ws, size_t ws_size,
                              hipStream_t stream) {
  const float* q    = (const float*)d_in[0];
  const float* knew = (const float*)d_in[1];
  const float* vnew = (const float*)d_in[2];
  const float* kc   = (const float*)d_in[3];
  const float* vc   = (const float*)d_in[4];
  const int*   kvi  = (const int*)d_in[5];
  float* out = (float*)d_out;

  if (ws_size >= WS_NEED_BYTES) {
    float* ws_o  = (float*)d_ws;
    float* ws_ms = ws_o + WS_O_FLOATS;
    attn_part<<<dim3(BB * SPLITS), dim3(NTHREADS), 0, stream>>>(
        q, knew, vnew, kc, vc, kvi, ws_o, ws_ms);
    attn_merge<<<dim3(BB * KHH), dim3(NTHREADS), 0, stream>>>(ws_o, ws_ms, out);
  } else {
    attn_decode_fb<<<dim3(BB * KHH), dim3(NTHREADS), 0, stream>>>(
        q, knew, vnew, kc, vc, kvi, out);
  }
}

// Round 6
// 189.521 us; speedup vs baseline: 1.0269x; 1.0269x over previous
//
#include <hip/hip_runtime.h>
#include <math.h>

#define BB 32
#define HH 32
#define KHH 8
#define DD 128
#define LL 4096
#define GG 4
#define SCALE 0.08838834764831845f

#define NTHREADS 512
#define NW 8                       // waves per block (2 waves/SIMD at 1 block/CU)
#define ROWS_PER_WAVE (LL / NW)    // 512
#define NIT (ROWS_PER_WAVE / 4)    // 128 iterations, 4 rows per wave-iter

// Best-measured configuration (R1, 189.3 µs = 5.67 TB/s effective).
// Five structural variants (2x TLP, 2-deep pipeline, nontemporal, XCD swizzle,
// contiguous-row split-K) all measured 5.5-5.7 TB/s -> structure-independent
// read-streaming plateau; this is the simplest/fastest point.
__global__ __launch_bounds__(NTHREADS)
void attn_decode(const float* __restrict__ q,
                 const float* __restrict__ knew,
                 const float* __restrict__ vnew,
                 const float* __restrict__ kc,
                 const float* __restrict__ vc,
                 const int* __restrict__ kvi,
                 float* __restrict__ out) {
  __shared__ int   lds_val[LL];          // 16 KB: encoded row source per l
  __shared__ float o_lds[NW][GG][DD];    // 16 KB: per-wave partial O
  __shared__ float m_lds[NW][GG];
  __shared__ float s_lds[NW][GG];
  __shared__ int   lds_loc[BB];

  const int tid  = threadIdx.x;
  const int b    = blockIdx.x >> 3;
  const int kh   = blockIdx.x & 7;
  const int w    = tid >> 6;
  const int lane = tid & 63;
  const int qid  = lane >> 4;   // quarter-wave id 0..3 (one row each per iter)
  const int i16  = lane & 15;   // lane within quarter: dims [8*i16, 8*i16+8)

  // ---- precompute row-source table: val>=0 -> cache row, val<0 -> new-kv batch -(val+1)
  if (tid < BB) lds_loc[tid] = kvi[tid * LL + (LL - 1)];
  __syncthreads();
  for (int l = tid; l < LL; l += NTHREADS) {
    int idx = kvi[b * LL + l];
    int val = idx;
#pragma unroll
    for (int j = 0; j < BB; ++j)
      if (lds_loc[j] == idx) val = -(j + 1);
    lds_val[l] = val;
  }
  __syncthreads();

  // ---- q fragments: 4 heads x 8 dims per lane
  const int khq = kh * GG;
  float qf[GG][8];
#pragma unroll
  for (int g = 0; g < GG; ++g) {
    const float* qp = q + ((size_t)b * HH + (khq + g)) * DD + i16 * 8;
#pragma unroll
    for (int j = 0; j < 8; ++j) qf[g][j] = qp[j];
  }

  float m[GG], s[GG], o[GG][8];
#pragma unroll
  for (int g = 0; g < GG; ++g) {
    m[g] = -INFINITY; s[g] = 0.f;
#pragma unroll
    for (int j = 0; j < 8; ++j) o[g][j] = 0.f;
  }

  const int    base  = w * ROWS_PER_WAVE;
  const size_t khoff = (size_t)kh * DD + i16 * 8;

  auto addr = [&](int it, const float*& kp, const float*& vp) {
    int l   = base + it * 4 + qid;
    int val = lds_val[l];
    int row = (val < 0) ? (-val - 1) : val;
    const float* kb = (val < 0) ? knew : kc;
    const float* vb = (val < 0) ? vnew : vc;
    size_t off = ((size_t)row * (KHH * DD)) + khoff;
    kp = kb + off;
    vp = vb + off;
  };

  // prologue load
  const float *kp, *vp;
  addr(0, kp, vp);
  float4 ka  = *(const float4*)kp;
  float4 kb4 = *(const float4*)(kp + 4);
  float4 va  = *(const float4*)vp;
  float4 vb4 = *(const float4*)(vp + 4);

  for (int it = 0; it < NIT; ++it) {
    float4 nka, nkb, nva, nvb;
    if (it + 1 < NIT) {            // 1-deep prefetch of next rows
      const float *nkp, *nvp;
      addr(it + 1, nkp, nvp);
      nka = *(const float4*)nkp;
      nkb = *(const float4*)(nkp + 4);
      nva = *(const float4*)nvp;
      nvb = *(const float4*)(nvp + 4);
    } else {
      nka = ka; nkb = kb4; nva = va; nvb = vb4;
    }

#pragma unroll
    for (int g = 0; g < GG; ++g) {
      float sc = qf[g][0]*ka.x  + qf[g][1]*ka.y  + qf[g][2]*ka.z  + qf[g][3]*ka.w
               + qf[g][4]*kb4.x + qf[g][5]*kb4.y + qf[g][6]*kb4.z + qf[g][7]*kb4.w;
#pragma unroll
      for (int msk = 1; msk < 16; msk <<= 1)
        sc += __shfl_xor(sc, msk);       // reduce across the 16-lane quarter
      sc *= SCALE;

      if (sc > m[g]) {                   // rare after warm-up; uniform per quarter
        float so = __expf(m[g] - sc);
        m[g] = sc;
        s[g] *= so;
#pragma unroll
        for (int j = 0; j < 8; ++j) o[g][j] *= so;
      }
      float p = __expf(sc - m[g]);
      s[g] += p;
      o[g][0] += p * va.x;  o[g][1] += p * va.y;  o[g][2] += p * va.z;  o[g][3] += p * va.w;
      o[g][4] += p * vb4.x; o[g][5] += p * vb4.y; o[g][6] += p * vb4.z; o[g][7] += p * vb4.w;
    }

    ka = nka; kb4 = nkb; va = nva; vb4 = nvb;
  }

  // ---- merge the 4 quarters within each wave (each quarter covers full D)
#pragma unroll
  for (int g = 0; g < GG; ++g) {
#pragma unroll
    for (int off = 16; off < 64; off <<= 1) {
      float m2 = __shfl_xor(m[g], off);
      float s2 = __shfl_xor(s[g], off);
      float M  = fmaxf(m[g], m2);
      float w1 = __expf(m[g] - M);
      float w2 = __expf(m2 - M);
      s[g] = w1 * s[g] + w2 * s2;
#pragma unroll
      for (int j = 0; j < 8; ++j) {
        float o2 = __shfl_xor(o[g][j], off);
        o[g][j] = w1 * o[g][j] + w2 * o2;
      }
      m[g] = M;
    }
  }

  // ---- per-wave partials to LDS
  if (lane < 16) {
#pragma unroll
    for (int g = 0; g < GG; ++g) {
#pragma unroll
      for (int j = 0; j < 8; ++j) o_lds[w][g][i16 * 8 + j] = o[g][j];
      if (lane == 0) { m_lds[w][g] = m[g]; s_lds[w][g] = s[g]; }
    }
  }
  __syncthreads();

  // ---- cross-wave combine + write: 512 threads -> (g, d)
  {
    int g = tid >> 7;
    int d = tid & 127;
    float M = -INFINITY;
#pragma unroll
    for (int wv = 0; wv < NW; ++wv) M = fmaxf(M, m_lds[wv][g]);
    float ss = 0.f, oo = 0.f;
#pragma unroll
    for (int wv = 0; wv < NW; ++wv) {
      float wt = __expf(m_lds[wv][g] - M);
      ss += wt * s_lds[wv][g];
      oo += wt * o_lds[wv][g][d];
    }
    out[((size_t)b * HH + (khq + g)) * DD + d] = oo / ss;
  }
}

extern "C" void kernel_launch(void* const* d_in, const int* in_sizes, int n_in,
                              void* d_out, int out_size, void* d_ws, size_t ws_size,
                              hipStream_t stream) {
  const float* q    = (const float*)d_in[0];
  const float* knew = (const float*)d_in[1];
  const float* vnew = (const float*)d_in[2];
  const float* kc   = (const float*)d_in[3];
  const float* vc   = (const float*)d_in[4];
  const int*   kvi  = (const int*)d_in[5];
  float* out = (float*)d_out;

  attn_decode<<<dim3(BB * KHH), dim3(NTHREADS), 0, stream>>>(q, knew, vnew, kc, vc, kvi, out);
}